// Round 2
// baseline (581.858 us; speedup 1.0000x reference)
//
#include <hip/hip_runtime.h>

#define NN 100000
#define NE 1600000
#define NF 512
#define NH 128
#define NC 64
#define NBH 782            // edge blocks, 2048 edges each (782*2048 >= NE)
#define CONVB 288          // weight-conversion blocks
#define NGB 782            // gemm1 tiles of 128 rows (782*128 >= NN)
#define NSB 98             // scan blocks of 1024 (98*1024 >= NN)

typedef __attribute__((ext_vector_type(8))) short bf16x8;
typedef __attribute__((ext_vector_type(4))) float f32x4;

static __device__ __forceinline__ unsigned short f2bf(float f) {
  unsigned int u = __float_as_uint(f);
  u += 0x7fffu + ((u >> 16) & 1u);   // RNE
  return (unsigned short)(u >> 16);
}
static __device__ __forceinline__ float bf2f(unsigned short s) {
  return __uint_as_float(((unsigned int)s) << 16);
}

// ---------------- zero per-node counts ----------------
__global__ __launch_bounds__(1024) void k_zero(int* __restrict__ rowcount) {
  int i = blockIdx.x * 1024 + threadIdx.x;
  if (i < NN) rowcount[i] = 0;
}

// ---------------- K1: per-node degree hist (global atomics) + weight conv ----------------
__global__ __launch_bounds__(256) void k_hist_conv(const int* __restrict__ ei,
                                                   int* __restrict__ rowcount,
                                                   const float* __restrict__ W1,
                                                   const float* __restrict__ W2,
                                                   unsigned short* __restrict__ W1t,
                                                   unsigned short* __restrict__ W2t) {
  int t = threadIdx.x;
  if (blockIdx.x < NBH) {
    int e8 = blockIdx.x * 2048 + t * 8;
    if (e8 + 8 <= NE) {
      int4 d0 = *(const int4*)(ei + NE + e8);
      int4 d1 = *(const int4*)(ei + NE + e8 + 4);
      atomicAdd(&rowcount[d0.x], 1); atomicAdd(&rowcount[d0.y], 1);
      atomicAdd(&rowcount[d0.z], 1); atomicAdd(&rowcount[d0.w], 1);
      atomicAdd(&rowcount[d1.x], 1); atomicAdd(&rowcount[d1.y], 1);
      atomicAdd(&rowcount[d1.z], 1); atomicAdd(&rowcount[d1.w], 1);
    } else {
      for (int k = 0; k < 8; ++k)
        if (e8 + k < NE) atomicAdd(&rowcount[ei[NE + e8 + k]], 1);
    }
  } else {
    int i = (blockIdx.x - NBH) * 256 + t;
    if (i < NF * NH) {
      int k = i / NH, n = i % NH;
      W1t[n * NF + k] = f2bf(W1[i]);
    }
    int j = i - NF * NH;
    if (j >= 0 && j < NH * NC) {
      int k = j / NC, n = j % NC;
      W2t[n * NH + k] = f2bf(W2[j]);
    }
  }
}

// ---------------- 2-level exclusive scan of rowcount -> rowptr ----------------
__global__ __launch_bounds__(1024) void k_scanA(const int* __restrict__ rowcount,
                                                int* __restrict__ rowptr,
                                                int* __restrict__ psum) {
  __shared__ int sd[1024];
  int t = threadIdx.x;
  int i = blockIdx.x * 1024 + t;
  int v = (i < NN) ? rowcount[i] : 0;
  sd[t] = v; __syncthreads();
  for (int o = 1; o < 1024; o <<= 1) {
    int y = (t >= o) ? sd[t - o] : 0;
    __syncthreads();
    sd[t] += y;
    __syncthreads();
  }
  if (i < NN) rowptr[i] = sd[t] - v;       // block-local exclusive
  if (t == 1023) psum[blockIdx.x] = sd[t]; // block total
}

__global__ __launch_bounds__(128) void k_scanB(int* __restrict__ psum,
                                               int* __restrict__ rowptr) {
  __shared__ int sd[128];
  int t = threadIdx.x;
  int v = (t < NSB) ? psum[t] : 0;
  sd[t] = v; __syncthreads();
  for (int o = 1; o < 128; o <<= 1) {
    int y = (t >= o) ? sd[t - o] : 0;
    __syncthreads();
    sd[t] += y;
    __syncthreads();
  }
  if (t < NSB) psum[t] = sd[t] - v;        // exclusive block offsets
  if (t == 0) rowptr[NN] = NE;
}

__global__ __launch_bounds__(1024) void k_fixup(int* __restrict__ rowptr,
                                                int* __restrict__ rowcursor,
                                                const int* __restrict__ psum) {
  int i = blockIdx.x * 1024 + threadIdx.x;
  if (i < NN) {
    int r = rowptr[i] + psum[blockIdx.x];
    rowptr[i] = r;
    rowcursor[i] = r;
  }
}

// ---------------- K3: GEMM1 (blocks 0..781) + direct edge scatter (blocks 782..1563) ----------------
// gemm1: h[NN][NH] bf16 = x[NN][NF] f32 @ W1 (128x128 tile, 16x16x32 MFMA)
// scatter: pos = atomicAdd(rowcursor[dst]); sedge[pos] = {src, w}
__global__ __launch_bounds__(256) void k_gemm1_scat(const float* __restrict__ x,
                                                    const unsigned short* __restrict__ W1t,
                                                    unsigned short* __restrict__ h,
                                                    const int* __restrict__ ei,
                                                    const float* __restrict__ ew,
                                                    int* __restrict__ rowcursor,
                                                    int2* __restrict__ sedge) {
  __shared__ __align__(16) char smem[36864];
  int t = threadIdx.x;
  if (blockIdx.x < NGB) {
    // ---- GEMM1 tile ----
    typedef unsigned short row72[72];
    row72* As = (row72*)smem;                       // 128 x 72 shorts
    row72* Bs = (row72*)(smem + 128 * 72 * 2);      // 128 x 72 shorts
    int rowBase = blockIdx.x * 128;
    int wave = t >> 6, lane = t & 63;
    int wm = (wave & 1) * 64, wn = (wave >> 1) * 64;
    int lrow = lane & 15, quad = lane >> 4;

    f32x4 acc[4][4];
#pragma unroll
    for (int i = 0; i < 4; ++i)
#pragma unroll
      for (int j = 0; j < 4; ++j) acc[i][j] = (f32x4){0.f, 0.f, 0.f, 0.f};

    for (int k0 = 0; k0 < NF; k0 += 64) {
#pragma unroll
      for (int i = 0; i < 8; ++i) {           // stage A: 128x64 f32 -> bf16
        int idx = t + i * 256;
        int r = idx >> 4, c4 = idx & 15;
        int row = rowBase + r; if (row >= NN) row = NN - 1;
        const float4 v = *(const float4*)(x + (size_t)row * NF + k0 + c4 * 4);
        ushort4 sv;
        sv.x = f2bf(v.x); sv.y = f2bf(v.y); sv.z = f2bf(v.z); sv.w = f2bf(v.w);
        *(ushort4*)(&As[r][c4 * 4]) = sv;
      }
#pragma unroll
      for (int i = 0; i < 8; ++i) {           // stage B: 128x64 bf16
        int idx = t + i * 256;
        int n = idx >> 4, c4 = idx & 15;
        *(ushort4*)(&Bs[n][c4 * 4]) = *(const ushort4*)(W1t + n * NF + k0 + c4 * 4);
      }
      __syncthreads();
#pragma unroll
      for (int ks = 0; ks < 64; ks += 32) {
        bf16x8 a[4], b[4];
#pragma unroll
        for (int mt = 0; mt < 4; ++mt) a[mt] = *(const bf16x8*)(&As[wm + mt * 16 + lrow][ks + quad * 8]);
#pragma unroll
        for (int nt = 0; nt < 4; ++nt) b[nt] = *(const bf16x8*)(&Bs[wn + nt * 16 + lrow][ks + quad * 8]);
#pragma unroll
        for (int mt = 0; mt < 4; ++mt)
#pragma unroll
          for (int nt = 0; nt < 4; ++nt)
            acc[mt][nt] = __builtin_amdgcn_mfma_f32_16x16x32_bf16(a[mt], b[nt], acc[mt][nt], 0, 0, 0);
      }
      __syncthreads();
    }
#pragma unroll
    for (int mt = 0; mt < 4; ++mt)
#pragma unroll
      for (int nt = 0; nt < 4; ++nt)
#pragma unroll
        for (int r = 0; r < 4; ++r) {
          int row = rowBase + wm + mt * 16 + quad * 4 + r;
          if (row < NN) {
            int col = wn + nt * 16 + lrow;
            h[(size_t)row * NH + col] = f2bf(acc[mt][nt][r]);
          }
        }
  } else {
    // ---- direct scatter: single pass over edges ----
    int e8 = (blockIdx.x - NGB) * 2048 + t * 8;
    if (e8 + 8 <= NE) {
      int4 s0 = *(const int4*)(ei + e8);
      int4 s1 = *(const int4*)(ei + e8 + 4);
      int4 d0 = *(const int4*)(ei + NE + e8);
      int4 d1 = *(const int4*)(ei + NE + e8 + 4);
      float4 w0 = *(const float4*)(ew + e8);
      float4 w1 = *(const float4*)(ew + e8 + 4);
      int p;
      p = atomicAdd(&rowcursor[d0.x], 1); sedge[p] = make_int2(s0.x, __float_as_int(w0.x));
      p = atomicAdd(&rowcursor[d0.y], 1); sedge[p] = make_int2(s0.y, __float_as_int(w0.y));
      p = atomicAdd(&rowcursor[d0.z], 1); sedge[p] = make_int2(s0.z, __float_as_int(w0.z));
      p = atomicAdd(&rowcursor[d0.w], 1); sedge[p] = make_int2(s0.w, __float_as_int(w0.w));
      p = atomicAdd(&rowcursor[d1.x], 1); sedge[p] = make_int2(s1.x, __float_as_int(w1.x));
      p = atomicAdd(&rowcursor[d1.y], 1); sedge[p] = make_int2(s1.y, __float_as_int(w1.y));
      p = atomicAdd(&rowcursor[d1.z], 1); sedge[p] = make_int2(s1.z, __float_as_int(w1.z));
      p = atomicAdd(&rowcursor[d1.w], 1); sedge[p] = make_int2(s1.w, __float_as_int(w1.w));
    } else {
      for (int k = 0; k < 8; ++k) {
        int e = e8 + k;
        if (e < NE) {
          int p = atomicAdd(&rowcursor[ei[NE + e]], 1);
          sedge[p] = make_int2(ei[e], __float_as_int(ew[e]));
        }
      }
    }
  }
}

// ---------------- GEMM2: h3[NN][NC] bf16 = h2[NN][NH] bf16 @ W2 ----------------
__global__ __launch_bounds__(256) void k_gemm2(const unsigned short* __restrict__ h2,
                                               const unsigned short* __restrict__ W2t,
                                               unsigned short* __restrict__ h3) {
  __shared__ __align__(16) unsigned short As[256][72];
  __shared__ __align__(16) unsigned short Bs[64][72];
  int t = threadIdx.x;
  int rowBase = blockIdx.x * 256;
  int wave = t >> 6, lane = t & 63;
  int wm = wave * 64;
  int lrow = lane & 15, quad = lane >> 4;

  f32x4 acc[4][4];
#pragma unroll
  for (int i = 0; i < 4; ++i)
#pragma unroll
    for (int j = 0; j < 4; ++j) acc[i][j] = (f32x4){0.f, 0.f, 0.f, 0.f};

  for (int k0 = 0; k0 < NH; k0 += 64) {
#pragma unroll
    for (int i = 0; i < 16; ++i) {          // stage A: 256x64 bf16
      int idx = t + i * 256;
      int r = idx >> 4, c4 = idx & 15;
      int row = rowBase + r; if (row >= NN) row = NN - 1;
      *(ushort4*)(&As[r][c4 * 4]) = *(const ushort4*)(h2 + (size_t)row * NH + k0 + c4 * 4);
    }
#pragma unroll
    for (int i = 0; i < 4; ++i) {           // stage B: 64x64 bf16
      int idx = t + i * 256;
      int n = idx >> 4, c4 = idx & 15;
      *(ushort4*)(&Bs[n][c4 * 4]) = *(const ushort4*)(W2t + n * NH + k0 + c4 * 4);
    }
    __syncthreads();
#pragma unroll
    for (int ks = 0; ks < 64; ks += 32) {
      bf16x8 a[4], b[4];
#pragma unroll
      for (int mt = 0; mt < 4; ++mt) a[mt] = *(const bf16x8*)(&As[wm + mt * 16 + lrow][ks + quad * 8]);
#pragma unroll
      for (int nt = 0; nt < 4; ++nt) b[nt] = *(const bf16x8*)(&Bs[nt * 16 + lrow][ks + quad * 8]);
#pragma unroll
      for (int mt = 0; mt < 4; ++mt)
#pragma unroll
        for (int nt = 0; nt < 4; ++nt)
          acc[mt][nt] = __builtin_amdgcn_mfma_f32_16x16x32_bf16(a[mt], b[nt], acc[mt][nt], 0, 0, 0);
    }
    __syncthreads();
  }
#pragma unroll
  for (int mt = 0; mt < 4; ++mt)
#pragma unroll
    for (int nt = 0; nt < 4; ++nt)
#pragma unroll
      for (int r = 0; r < 4; ++r) {
        int row = rowBase + wm + mt * 16 + quad * 4 + r;
        if (row < NN) {
          int col = nt * 16 + lrow;
          h3[(size_t)row * NC + col] = f2bf(acc[mt][nt][r]);
        }
      }
}

// ---------------- propagate 1: h2 = relu(seg_sum(w * h[src]) + b1), D=128 ----------------
// 16 lanes/edge x uint4(16B), 4 edge slots x 2-unroll = 8 gathers in flight per wave
__global__ __launch_bounds__(256) void k_prop1(const int* __restrict__ rowptr,
                                               const int2* __restrict__ sedge,
                                               const unsigned short* __restrict__ h,
                                               const float* __restrict__ b1,
                                               unsigned short* __restrict__ h2) {
  __shared__ int2 se[4][64];
  int w = threadIdx.x >> 6, lane = threadIdx.x & 63;
  int q = lane >> 4, l4 = lane & 15;
  int node = blockIdx.x * 4 + w;
  int e0 = rowptr[node], e1 = rowptr[node + 1];
  float a[8];
#pragma unroll
  for (int k = 0; k < 8; ++k) a[k] = 0.f;
  for (int e = e0; e < e1; e += 64) {
    int cnt = e1 - e; if (cnt > 64) cnt = 64;
    if (lane < cnt) se[w][lane] = sedge[e + lane];
    asm volatile("s_waitcnt lgkmcnt(0)" ::: "memory");
    for (int j = 0; j < cnt; j += 8) {
      int i0 = j + q, i1 = j + 4 + q;                 // both <= 63 always
      int2 ed0 = (i0 < cnt) ? se[w][i0] : make_int2(0, 0);
      int2 ed1 = (i1 < cnt) ? se[w][i1] : make_int2(0, 0);
      float w0 = __int_as_float(ed0.y), w1 = __int_as_float(ed1.y);
      uint4 v0 = *(const uint4*)(h + (size_t)ed0.x * NH + l4 * 8);
      uint4 v1 = *(const uint4*)(h + (size_t)ed1.x * NH + l4 * 8);
      a[0] += w0 * bf2f((unsigned short)(v0.x & 0xffffu));
      a[1] += w0 * bf2f((unsigned short)(v0.x >> 16));
      a[2] += w0 * bf2f((unsigned short)(v0.y & 0xffffu));
      a[3] += w0 * bf2f((unsigned short)(v0.y >> 16));
      a[4] += w0 * bf2f((unsigned short)(v0.z & 0xffffu));
      a[5] += w0 * bf2f((unsigned short)(v0.z >> 16));
      a[6] += w0 * bf2f((unsigned short)(v0.w & 0xffffu));
      a[7] += w0 * bf2f((unsigned short)(v0.w >> 16));
      a[0] += w1 * bf2f((unsigned short)(v1.x & 0xffffu));
      a[1] += w1 * bf2f((unsigned short)(v1.x >> 16));
      a[2] += w1 * bf2f((unsigned short)(v1.y & 0xffffu));
      a[3] += w1 * bf2f((unsigned short)(v1.y >> 16));
      a[4] += w1 * bf2f((unsigned short)(v1.z & 0xffffu));
      a[5] += w1 * bf2f((unsigned short)(v1.z >> 16));
      a[6] += w1 * bf2f((unsigned short)(v1.w & 0xffffu));
      a[7] += w1 * bf2f((unsigned short)(v1.w >> 16));
    }
  }
#pragma unroll
  for (int k = 0; k < 8; ++k) {
    a[k] += __shfl_xor(a[k], 16);
    a[k] += __shfl_xor(a[k], 32);
  }
  if (q == 0) {
    float4 ba = *(const float4*)(b1 + l4 * 8);
    float4 bb = *(const float4*)(b1 + l4 * 8 + 4);
    float o0 = fmaxf(a[0] + ba.x, 0.f), o1 = fmaxf(a[1] + ba.y, 0.f);
    float o2 = fmaxf(a[2] + ba.z, 0.f), o3 = fmaxf(a[3] + ba.w, 0.f);
    float o4 = fmaxf(a[4] + bb.x, 0.f), o5 = fmaxf(a[5] + bb.y, 0.f);
    float o6 = fmaxf(a[6] + bb.z, 0.f), o7 = fmaxf(a[7] + bb.w, 0.f);
    uint4 pk;
    pk.x = ((unsigned int)f2bf(o1) << 16) | (unsigned int)f2bf(o0);
    pk.y = ((unsigned int)f2bf(o3) << 16) | (unsigned int)f2bf(o2);
    pk.z = ((unsigned int)f2bf(o5) << 16) | (unsigned int)f2bf(o4);
    pk.w = ((unsigned int)f2bf(o7) << 16) | (unsigned int)f2bf(o6);
    *(uint4*)(h2 + (size_t)node * NH + l4 * 8) = pk;
  }
}

// ---------------- propagate 2: out = seg_sum(w * h3[src]) + b2, D=64 ----------------
// 8 lanes/edge x uint4(16B), 8 edge slots x 2-unroll = 16 gathers in flight per wave
__global__ __launch_bounds__(256) void k_prop2(const int* __restrict__ rowptr,
                                               const int2* __restrict__ sedge,
                                               const unsigned short* __restrict__ h3,
                                               const float* __restrict__ b2,
                                               float* __restrict__ out) {
  __shared__ int2 se[4][64];
  int w = threadIdx.x >> 6, lane = threadIdx.x & 63;
  int o = lane >> 3, l8 = lane & 7;
  int node = blockIdx.x * 4 + w;
  int e0 = rowptr[node], e1 = rowptr[node + 1];
  float a[8];
#pragma unroll
  for (int k = 0; k < 8; ++k) a[k] = 0.f;
  for (int e = e0; e < e1; e += 64) {
    int cnt = e1 - e; if (cnt > 64) cnt = 64;
    if (lane < cnt) se[w][lane] = sedge[e + lane];
    asm volatile("s_waitcnt lgkmcnt(0)" ::: "memory");
    for (int j = 0; j < cnt; j += 16) {
      int i0 = j + o, i1 = j + 8 + o;                 // both <= 63 always
      int2 ed0 = (i0 < cnt) ? se[w][i0] : make_int2(0, 0);
      int2 ed1 = (i1 < cnt) ? se[w][i1] : make_int2(0, 0);
      float w0 = __int_as_float(ed0.y), w1 = __int_as_float(ed1.y);
      uint4 v0 = *(const uint4*)(h3 + (size_t)ed0.x * NC + l8 * 8);
      uint4 v1 = *(const uint4*)(h3 + (size_t)ed1.x * NC + l8 * 8);
      a[0] += w0 * bf2f((unsigned short)(v0.x & 0xffffu));
      a[1] += w0 * bf2f((unsigned short)(v0.x >> 16));
      a[2] += w0 * bf2f((unsigned short)(v0.y & 0xffffu));
      a[3] += w0 * bf2f((unsigned short)(v0.y >> 16));
      a[4] += w0 * bf2f((unsigned short)(v0.z & 0xffffu));
      a[5] += w0 * bf2f((unsigned short)(v0.z >> 16));
      a[6] += w0 * bf2f((unsigned short)(v0.w & 0xffffu));
      a[7] += w0 * bf2f((unsigned short)(v0.w >> 16));
      a[0] += w1 * bf2f((unsigned short)(v1.x & 0xffffu));
      a[1] += w1 * bf2f((unsigned short)(v1.x >> 16));
      a[2] += w1 * bf2f((unsigned short)(v1.y & 0xffffu));
      a[3] += w1 * bf2f((unsigned short)(v1.y >> 16));
      a[4] += w1 * bf2f((unsigned short)(v1.z & 0xffffu));
      a[5] += w1 * bf2f((unsigned short)(v1.z >> 16));
      a[6] += w1 * bf2f((unsigned short)(v1.w & 0xffffu));
      a[7] += w1 * bf2f((unsigned short)(v1.w >> 16));
    }
  }
#pragma unroll
  for (int k = 0; k < 8; ++k) {
    a[k] += __shfl_xor(a[k], 8);
    a[k] += __shfl_xor(a[k], 16);
    a[k] += __shfl_xor(a[k], 32);
  }
  if (o == 0) {
    float4 c0 = *(const float4*)(b2 + l8 * 8);
    float4 c1 = *(const float4*)(b2 + l8 * 8 + 4);
    float4 r0 = make_float4(a[0] + c0.x, a[1] + c0.y, a[2] + c0.z, a[3] + c0.w);
    float4 r1 = make_float4(a[4] + c1.x, a[5] + c1.y, a[6] + c1.z, a[7] + c1.w);
    *(float4*)(out + (size_t)node * NC + l8 * 8) = r0;
    *(float4*)(out + (size_t)node * NC + l8 * 8 + 4) = r1;
  }
}

extern "C" void kernel_launch(void* const* d_in, const int* in_sizes, int n_in,
                              void* d_out, int out_size, void* d_ws, size_t ws_size,
                              hipStream_t stream) {
  const float* x = (const float*)d_in[0];
  const int* ei = (const int*)d_in[1];   // int32 on device (harness convention)
  const float* ew = (const float*)d_in[2];
  const float* W1 = (const float*)d_in[3];
  const float* b1 = (const float*)d_in[4];
  const float* W2 = (const float*)d_in[5];
  const float* b2 = (const float*)d_in[6];
  float* out = (float*)d_out;

  char* ws = (char*)d_ws;
  size_t off = 0;
  auto alloc = [&](size_t bytes) {
    char* p = ws + off;
    off = (off + bytes + 255) & ~(size_t)255;
    return p;
  };
  unsigned short* W1t = (unsigned short*)alloc((size_t)NF * NH * 2);
  unsigned short* W2t = (unsigned short*)alloc((size_t)NH * NC * 2);
  unsigned short* h   = (unsigned short*)alloc((size_t)NN * NH * 2);
  unsigned short* h2  = (unsigned short*)alloc((size_t)NN * NH * 2);
  unsigned short* h3  = h;  // h dead after prop1; alias to save ws
  int* rowptr    = (int*)alloc((size_t)(NN + 1) * 4);
  int* rowcount  = (int*)alloc((size_t)NN * 4);
  int* rowcursor = (int*)alloc((size_t)NN * 4);
  int* psum      = (int*)alloc(128 * 4);
  int2* sedge    = (int2*)alloc((size_t)NE * 8);

  k_zero<<<NSB, 1024, 0, stream>>>(rowcount);
  k_hist_conv<<<NBH + CONVB, 256, 0, stream>>>(ei, rowcount, W1, W2, W1t, W2t);
  k_scanA<<<NSB, 1024, 0, stream>>>(rowcount, rowptr, psum);
  k_scanB<<<1, 128, 0, stream>>>(psum, rowptr);
  k_fixup<<<NSB, 1024, 0, stream>>>(rowptr, rowcursor, psum);
  k_gemm1_scat<<<NGB + NBH, 256, 0, stream>>>(x, W1t, h, ei, ew, rowcursor, sedge);
  k_prop1<<<NN / 4, 256, 0, stream>>>(rowptr, sedge, h, b1, h2);
  k_gemm2<<<(NN + 255) / 256, 256, 0, stream>>>(h2, W2t, h3);
  k_prop2<<<NN / 4, 256, 0, stream>>>(rowptr, sedge, h3, b2, out);
}

// Round 3
// 483.820 us; speedup vs baseline: 1.2026x; 1.2026x over previous
//
#include <hip/hip_runtime.h>

#define NN 100000
#define NE 1600000
#define NF 512
#define NH 128
#define NC 64
#define NPART 782            // ceil(NN/128): partition = dst>>7 (128 nodes each)
#define NBH 782              // hist blocks, 2048 edges each
#define NBP 196              // part blocks, 8192 edges each
#define CONVB 288            // weight-conversion blocks
#define SORTBUF 2816         // partition size ~2048 +- 45 (17 sigma margin)

typedef __attribute__((ext_vector_type(8))) short bf16x8;
typedef __attribute__((ext_vector_type(4))) float f32x4;

static __device__ __forceinline__ unsigned short f2bf(float f) {
  unsigned int u = __float_as_uint(f);
  u += 0x7fffu + ((u >> 16) & 1u);   // RNE
  return (unsigned short)(u >> 16);
}
static __device__ __forceinline__ float bf2f(unsigned short s) {
  return __uint_as_float(((unsigned int)s) << 16);
}

// ---------------- zero partition totals ----------------
__global__ void k_zero0(int* __restrict__ p) {
  int i = blockIdx.x * 256 + threadIdx.x;
  if (i < NPART + 1) p[i] = 0;
}

// ---------------- K1: partition histogram (blocks 0..781) + weight conv (782..1069) ----------------
__global__ __launch_bounds__(256) void k_hist_conv(const int* __restrict__ ei,
                                                   int* __restrict__ partTotals,
                                                   const float* __restrict__ W1,
                                                   const float* __restrict__ W2,
                                                   unsigned short* __restrict__ W1t,
                                                   unsigned short* __restrict__ W2t) {
  int t = threadIdx.x;
  if (blockIdx.x < NBH) {
    __shared__ int hist[NPART];
    for (int i = t; i < NPART; i += 256) hist[i] = 0;
    __syncthreads();
    int base = blockIdx.x * 2048;
#pragma unroll
    for (int j = 0; j < 8; ++j) {
      int e = base + j * 256 + t;
      if (e < NE) atomicAdd(&hist[ei[NE + e] >> 7], 1);
    }
    __syncthreads();
    for (int i = t; i < NPART; i += 256)
      if (hist[i]) atomicAdd(&partTotals[i], hist[i]);
  } else {
    int i = (blockIdx.x - NBH) * 256 + t;
    if (i < NF * NH) {
      int k = i / NH, n = i % NH;
      W1t[n * NF + k] = f2bf(W1[i]);
    }
    int j = i - NF * NH;
    if (j >= 0 && j < NH * NC) {
      int k = j / NC, n = j % NC;
      W2t[n * NH + k] = f2bf(W2[j]);
    }
  }
}

// ---------------- scan partition totals -> starts & cursors ----------------
__global__ __launch_bounds__(1024) void k_pscan(const int* __restrict__ partTotals,
                                                int* __restrict__ partStart,
                                                int* __restrict__ partCursor,
                                                int* __restrict__ rowptr) {
  __shared__ int sd[1024];
  int t = threadIdx.x;
  int v = (t < NPART) ? partTotals[t] : 0;
  sd[t] = v; __syncthreads();
  for (int o = 1; o < 1024; o <<= 1) {
    int y = (t >= o) ? sd[t - o] : 0;
    __syncthreads();
    sd[t] += y;
    __syncthreads();
  }
  int excl = sd[t] - v;
  if (t < NPART) { partStart[t] = excl; partCursor[t] = excl; }
  if (t == NPART - 1) partStart[NPART] = sd[t];  // == NE
  if (t == 0) rowptr[NN] = NE;
}

// ---------------- K3: edge partition pass (blocks 0..195) + GEMM1 (blocks 196..977) ----------------
// gemm1: h[NN][NH] bf16 = x[NN][NF] f32 @ W1 (128x128 tile, 16x16x32 MFMA)
// A-tile (x rows) is register-prefetched one K-step ahead so HBM latency hides under MFMA.
__global__ __launch_bounds__(256) void k_part_gemm1(const int* __restrict__ ei,
                                                    const float* __restrict__ ew,
                                                    int* __restrict__ partCursor,
                                                    int2* __restrict__ tmp,
                                                    const float* __restrict__ x,
                                                    const unsigned short* __restrict__ W1t,
                                                    unsigned short* __restrict__ h) {
  __shared__ __align__(16) char smem[36864];
  int t = threadIdx.x;
  if (blockIdx.x < NBP) {
    // ---- edge partitioning: 8192 edges, two global passes, run-coalesced writes ----
    int* hist = (int*)smem;           // NPART ints
    int* cur = hist + NPART;          // NPART ints
    for (int i = t; i < NPART; i += 256) hist[i] = 0;
    __syncthreads();
    int base = blockIdx.x * 8192;
#pragma unroll
    for (int j = 0; j < 32; ++j) {
      int e = base + j * 256 + t;
      if (e < NE) atomicAdd(&hist[ei[NE + e] >> 7], 1);
    }
    __syncthreads();
    for (int i = t; i < NPART; i += 256) {
      int c = hist[i];
      cur[i] = c ? atomicAdd(&partCursor[i], c) : 0;
    }
    __syncthreads();
#pragma unroll
    for (int j = 0; j < 32; ++j) {
      int e = base + j * 256 + t;
      if (e < NE) {
        int d = ei[NE + e];
        int pos = atomicAdd(&cur[d >> 7], 1);
        // pack: src (bits 0..16) | dst_local (bits 20..26); w bits in .y
        tmp[pos] = make_int2(ei[e] | ((d & 127) << 20), __float_as_int(ew[e]));
      }
    }
  } else {
    // ---- GEMM1 tile ----
    typedef unsigned short row72[72];
    row72* As = (row72*)smem;                       // 128 x 72 shorts
    row72* Bs = (row72*)(smem + 128 * 72 * 2);      // 128 x 72 shorts
    int rowBase = (blockIdx.x - NBP) * 128;
    int wave = t >> 6, lane = t & 63;
    int wm = (wave & 1) * 64, wn = (wave >> 1) * 64;
    int lrow = lane & 15, quad = lane >> 4;
    int r0 = t >> 4, c4 = t & 15;     // staging coords: rows r0+i*16, col block c4

    f32x4 acc[4][4];
#pragma unroll
    for (int i = 0; i < 4; ++i)
#pragma unroll
      for (int j = 0; j < 4; ++j) acc[i][j] = (f32x4){0.f, 0.f, 0.f, 0.f};

    // prologue: prefetch A regs for k0 = 0
    float4 pa[8];
#pragma unroll
    for (int i = 0; i < 8; ++i) {
      int row = rowBase + r0 + i * 16; if (row >= NN) row = NN - 1;
      pa[i] = *(const float4*)(x + (size_t)row * NF + c4 * 4);
    }

    for (int k0 = 0; k0 < NF; k0 += 64) {
#pragma unroll
      for (int i = 0; i < 8; ++i) {           // stage A from prefetched regs (cvt to bf16)
        int r = r0 + i * 16;
        ushort4 sv;
        sv.x = f2bf(pa[i].x); sv.y = f2bf(pa[i].y); sv.z = f2bf(pa[i].z); sv.w = f2bf(pa[i].w);
        *(ushort4*)(&As[r][c4 * 4]) = sv;
      }
#pragma unroll
      for (int i = 0; i < 8; ++i) {           // stage B: 128x64 bf16 (L2-hot W1t)
        int n = r0 + i * 16;
        *(ushort4*)(&Bs[n][c4 * 4]) = *(const ushort4*)(W1t + n * NF + k0 + c4 * 4);
      }
      __syncthreads();
      if (k0 + 64 < NF) {                     // issue next-step A loads; latency hides under MFMA
#pragma unroll
        for (int i = 0; i < 8; ++i) {
          int row = rowBase + r0 + i * 16; if (row >= NN) row = NN - 1;
          pa[i] = *(const float4*)(x + (size_t)row * NF + (k0 + 64) + c4 * 4);
        }
      }
#pragma unroll
      for (int ks = 0; ks < 64; ks += 32) {
        bf16x8 a[4], b[4];
#pragma unroll
        for (int mt = 0; mt < 4; ++mt) a[mt] = *(const bf16x8*)(&As[wm + mt * 16 + lrow][ks + quad * 8]);
#pragma unroll
        for (int nt = 0; nt < 4; ++nt) b[nt] = *(const bf16x8*)(&Bs[wn + nt * 16 + lrow][ks + quad * 8]);
#pragma unroll
        for (int mt = 0; mt < 4; ++mt)
#pragma unroll
          for (int nt = 0; nt < 4; ++nt)
            acc[mt][nt] = __builtin_amdgcn_mfma_f32_16x16x32_bf16(a[mt], b[nt], acc[mt][nt], 0, 0, 0);
      }
      __syncthreads();
    }
#pragma unroll
    for (int mt = 0; mt < 4; ++mt)
#pragma unroll
      for (int nt = 0; nt < 4; ++nt)
#pragma unroll
        for (int r = 0; r < 4; ++r) {
          int row = rowBase + wm + mt * 16 + quad * 4 + r;
          if (row < NN) {
            int col = wn + nt * 16 + lrow;
            h[(size_t)row * NH + col] = f2bf(acc[mt][nt][r]);
          }
        }
  }
}

// ---------------- pass B: per-partition counting sort by node (128 bins) ----------------
__global__ __launch_bounds__(256) void k_sortp(const int* __restrict__ partStart,
                                               const int2* __restrict__ tmp,
                                               int2* __restrict__ sedge,
                                               int* __restrict__ rowptr) {
  __shared__ int cnt[128];
  __shared__ int sc[128];
  __shared__ int wcur[128];
  __shared__ int2 sorted[SORTBUF];
  int p = blockIdx.x, t = threadIdx.x;
  int r0 = partStart[p], r1 = partStart[p + 1];
  int n = r1 - r0;
  if (t < 128) cnt[t] = 0;
  __syncthreads();
  for (int i = t; i < n; i += 256) {
    int2 v = tmp[r0 + i];
    atomicAdd(&cnt[v.x >> 20], 1);
  }
  __syncthreads();
  if (t < 128) sc[t] = cnt[t];
  __syncthreads();
  for (int o = 1; o < 128; o <<= 1) {
    int y = (t >= o && t < 128) ? sc[t - o] : 0;
    __syncthreads();
    if (t < 128) sc[t] += y;
    __syncthreads();
  }
  if (t < 128) {
    int excl = sc[t] - cnt[t];
    int node = p * 128 + t;
    if (node < NN) rowptr[node] = r0 + excl;
    wcur[t] = excl;
  }
  __syncthreads();
  for (int i = t; i < n; i += 256) {
    int2 v = tmp[r0 + i];                       // L2-hot re-read
    int lpos = atomicAdd(&wcur[v.x >> 20], 1);
    sorted[lpos] = make_int2(v.x & 0xFFFFF, v.y);
  }
  __syncthreads();
  for (int i = t; i < n; i += 256) sedge[r0 + i] = sorted[i];
}

// ---------------- GEMM2: h3[NN][NC] bf16 = h2[NN][NH] bf16 @ W2 ----------------
__global__ __launch_bounds__(256) void k_gemm2(const unsigned short* __restrict__ h2,
                                               const unsigned short* __restrict__ W2t,
                                               unsigned short* __restrict__ h3) {
  __shared__ __align__(16) unsigned short As[256][72];
  __shared__ __align__(16) unsigned short Bs[64][72];
  int t = threadIdx.x;
  int rowBase = blockIdx.x * 256;
  int wave = t >> 6, lane = t & 63;
  int wm = wave * 64;
  int lrow = lane & 15, quad = lane >> 4;

  f32x4 acc[4][4];
#pragma unroll
  for (int i = 0; i < 4; ++i)
#pragma unroll
    for (int j = 0; j < 4; ++j) acc[i][j] = (f32x4){0.f, 0.f, 0.f, 0.f};

  for (int k0 = 0; k0 < NH; k0 += 64) {
#pragma unroll
    for (int i = 0; i < 16; ++i) {          // stage A: 256x64 bf16
      int idx = t + i * 256;
      int r = idx >> 4, c4 = idx & 15;
      int row = rowBase + r; if (row >= NN) row = NN - 1;
      *(ushort4*)(&As[r][c4 * 4]) = *(const ushort4*)(h2 + (size_t)row * NH + k0 + c4 * 4);
    }
#pragma unroll
    for (int i = 0; i < 4; ++i) {           // stage B: 64x64 bf16
      int idx = t + i * 256;
      int n = idx >> 4, c4 = idx & 15;
      *(ushort4*)(&Bs[n][c4 * 4]) = *(const ushort4*)(W2t + n * NH + k0 + c4 * 4);
    }
    __syncthreads();
#pragma unroll
    for (int ks = 0; ks < 64; ks += 32) {
      bf16x8 a[4], b[4];
#pragma unroll
      for (int mt = 0; mt < 4; ++mt) a[mt] = *(const bf16x8*)(&As[wm + mt * 16 + lrow][ks + quad * 8]);
#pragma unroll
      for (int nt = 0; nt < 4; ++nt) b[nt] = *(const bf16x8*)(&Bs[nt * 16 + lrow][ks + quad * 8]);
#pragma unroll
      for (int mt = 0; mt < 4; ++mt)
#pragma unroll
        for (int nt = 0; nt < 4; ++nt)
          acc[mt][nt] = __builtin_amdgcn_mfma_f32_16x16x32_bf16(a[mt], b[nt], acc[mt][nt], 0, 0, 0);
    }
    __syncthreads();
  }
#pragma unroll
  for (int mt = 0; mt < 4; ++mt)
#pragma unroll
    for (int nt = 0; nt < 4; ++nt)
#pragma unroll
      for (int r = 0; r < 4; ++r) {
        int row = rowBase + wm + mt * 16 + quad * 4 + r;
        if (row < NN) {
          int col = nt * 16 + lrow;
          h3[(size_t)row * NC + col] = f2bf(acc[mt][nt][r]);
        }
      }
}

// ---------------- propagate 1: h2 = relu(seg_sum(w * h[src]) + b1), D=128 ----------------
// 16 lanes/edge x uint4(16B), 4 edge slots x 2-unroll = 8 gathers in flight per wave
__global__ __launch_bounds__(256) void k_prop1(const int* __restrict__ rowptr,
                                               const int2* __restrict__ sedge,
                                               const unsigned short* __restrict__ h,
                                               const float* __restrict__ b1,
                                               unsigned short* __restrict__ h2) {
  __shared__ int2 se[4][64];
  int w = threadIdx.x >> 6, lane = threadIdx.x & 63;
  int q = lane >> 4, l4 = lane & 15;
  int node = blockIdx.x * 4 + w;
  int e0 = rowptr[node], e1 = rowptr[node + 1];
  float a[8];
#pragma unroll
  for (int k = 0; k < 8; ++k) a[k] = 0.f;
  for (int e = e0; e < e1; e += 64) {
    int cnt = e1 - e; if (cnt > 64) cnt = 64;
    if (lane < cnt) se[w][lane] = sedge[e + lane];
    asm volatile("s_waitcnt lgkmcnt(0)" ::: "memory");
    for (int j = 0; j < cnt; j += 8) {
      int i0 = j + q, i1 = j + 4 + q;                 // both <= 63 always
      int2 ed0 = (i0 < cnt) ? se[w][i0] : make_int2(0, 0);
      int2 ed1 = (i1 < cnt) ? se[w][i1] : make_int2(0, 0);
      float w0 = __int_as_float(ed0.y), w1 = __int_as_float(ed1.y);
      uint4 v0 = *(const uint4*)(h + (size_t)ed0.x * NH + l4 * 8);
      uint4 v1 = *(const uint4*)(h + (size_t)ed1.x * NH + l4 * 8);
      a[0] += w0 * bf2f((unsigned short)(v0.x & 0xffffu));
      a[1] += w0 * bf2f((unsigned short)(v0.x >> 16));
      a[2] += w0 * bf2f((unsigned short)(v0.y & 0xffffu));
      a[3] += w0 * bf2f((unsigned short)(v0.y >> 16));
      a[4] += w0 * bf2f((unsigned short)(v0.z & 0xffffu));
      a[5] += w0 * bf2f((unsigned short)(v0.z >> 16));
      a[6] += w0 * bf2f((unsigned short)(v0.w & 0xffffu));
      a[7] += w0 * bf2f((unsigned short)(v0.w >> 16));
      a[0] += w1 * bf2f((unsigned short)(v1.x & 0xffffu));
      a[1] += w1 * bf2f((unsigned short)(v1.x >> 16));
      a[2] += w1 * bf2f((unsigned short)(v1.y & 0xffffu));
      a[3] += w1 * bf2f((unsigned short)(v1.y >> 16));
      a[4] += w1 * bf2f((unsigned short)(v1.z & 0xffffu));
      a[5] += w1 * bf2f((unsigned short)(v1.z >> 16));
      a[6] += w1 * bf2f((unsigned short)(v1.w & 0xffffu));
      a[7] += w1 * bf2f((unsigned short)(v1.w >> 16));
    }
  }
#pragma unroll
  for (int k = 0; k < 8; ++k) {
    a[k] += __shfl_xor(a[k], 16);
    a[k] += __shfl_xor(a[k], 32);
  }
  if (q == 0) {
    float4 ba = *(const float4*)(b1 + l4 * 8);
    float4 bb = *(const float4*)(b1 + l4 * 8 + 4);
    float o0 = fmaxf(a[0] + ba.x, 0.f), o1 = fmaxf(a[1] + ba.y, 0.f);
    float o2 = fmaxf(a[2] + ba.z, 0.f), o3 = fmaxf(a[3] + ba.w, 0.f);
    float o4 = fmaxf(a[4] + bb.x, 0.f), o5 = fmaxf(a[5] + bb.y, 0.f);
    float o6 = fmaxf(a[6] + bb.z, 0.f), o7 = fmaxf(a[7] + bb.w, 0.f);
    uint4 pk;
    pk.x = ((unsigned int)f2bf(o1) << 16) | (unsigned int)f2bf(o0);
    pk.y = ((unsigned int)f2bf(o3) << 16) | (unsigned int)f2bf(o2);
    pk.z = ((unsigned int)f2bf(o5) << 16) | (unsigned int)f2bf(o4);
    pk.w = ((unsigned int)f2bf(o7) << 16) | (unsigned int)f2bf(o6);
    *(uint4*)(h2 + (size_t)node * NH + l4 * 8) = pk;
  }
}

// ---------------- propagate 2: out = seg_sum(w * h3[src]) + b2, D=64 ----------------
// 8 lanes/edge x uint4(16B), 8 edge slots x 2-unroll = 16 gathers in flight per wave
__global__ __launch_bounds__(256) void k_prop2(const int* __restrict__ rowptr,
                                               const int2* __restrict__ sedge,
                                               const unsigned short* __restrict__ h3,
                                               const float* __restrict__ b2,
                                               float* __restrict__ out) {
  __shared__ int2 se[4][64];
  int w = threadIdx.x >> 6, lane = threadIdx.x & 63;
  int o = lane >> 3, l8 = lane & 7;
  int node = blockIdx.x * 4 + w;
  int e0 = rowptr[node], e1 = rowptr[node + 1];
  float a[8];
#pragma unroll
  for (int k = 0; k < 8; ++k) a[k] = 0.f;
  for (int e = e0; e < e1; e += 64) {
    int cnt = e1 - e; if (cnt > 64) cnt = 64;
    if (lane < cnt) se[w][lane] = sedge[e + lane];
    asm volatile("s_waitcnt lgkmcnt(0)" ::: "memory");
    for (int j = 0; j < cnt; j += 16) {
      int i0 = j + o, i1 = j + 8 + o;                 // both <= 63 always
      int2 ed0 = (i0 < cnt) ? se[w][i0] : make_int2(0, 0);
      int2 ed1 = (i1 < cnt) ? se[w][i1] : make_int2(0, 0);
      float w0 = __int_as_float(ed0.y), w1 = __int_as_float(ed1.y);
      uint4 v0 = *(const uint4*)(h3 + (size_t)ed0.x * NC + l8 * 8);
      uint4 v1 = *(const uint4*)(h3 + (size_t)ed1.x * NC + l8 * 8);
      a[0] += w0 * bf2f((unsigned short)(v0.x & 0xffffu));
      a[1] += w0 * bf2f((unsigned short)(v0.x >> 16));
      a[2] += w0 * bf2f((unsigned short)(v0.y & 0xffffu));
      a[3] += w0 * bf2f((unsigned short)(v0.y >> 16));
      a[4] += w0 * bf2f((unsigned short)(v0.z & 0xffffu));
      a[5] += w0 * bf2f((unsigned short)(v0.z >> 16));
      a[6] += w0 * bf2f((unsigned short)(v0.w & 0xffffu));
      a[7] += w0 * bf2f((unsigned short)(v0.w >> 16));
      a[0] += w1 * bf2f((unsigned short)(v1.x & 0xffffu));
      a[1] += w1 * bf2f((unsigned short)(v1.x >> 16));
      a[2] += w1 * bf2f((unsigned short)(v1.y & 0xffffu));
      a[3] += w1 * bf2f((unsigned short)(v1.y >> 16));
      a[4] += w1 * bf2f((unsigned short)(v1.z & 0xffffu));
      a[5] += w1 * bf2f((unsigned short)(v1.z >> 16));
      a[6] += w1 * bf2f((unsigned short)(v1.w & 0xffffu));
      a[7] += w1 * bf2f((unsigned short)(v1.w >> 16));
    }
  }
#pragma unroll
  for (int k = 0; k < 8; ++k) {
    a[k] += __shfl_xor(a[k], 8);
    a[k] += __shfl_xor(a[k], 16);
    a[k] += __shfl_xor(a[k], 32);
  }
  if (o == 0) {
    float4 c0 = *(const float4*)(b2 + l8 * 8);
    float4 c1 = *(const float4*)(b2 + l8 * 8 + 4);
    float4 r0 = make_float4(a[0] + c0.x, a[1] + c0.y, a[2] + c0.z, a[3] + c0.w);
    float4 r1 = make_float4(a[4] + c1.x, a[5] + c1.y, a[6] + c1.z, a[7] + c1.w);
    *(float4*)(out + (size_t)node * NC + l8 * 8) = r0;
    *(float4*)(out + (size_t)node * NC + l8 * 8 + 4) = r1;
  }
}

extern "C" void kernel_launch(void* const* d_in, const int* in_sizes, int n_in,
                              void* d_out, int out_size, void* d_ws, size_t ws_size,
                              hipStream_t stream) {
  const float* x = (const float*)d_in[0];
  const int* ei = (const int*)d_in[1];   // int32 on device (harness convention)
  const float* ew = (const float*)d_in[2];
  const float* W1 = (const float*)d_in[3];
  const float* b1 = (const float*)d_in[4];
  const float* W2 = (const float*)d_in[5];
  const float* b2 = (const float*)d_in[6];
  float* out = (float*)d_out;

  char* ws = (char*)d_ws;
  size_t off = 0;
  auto alloc = [&](size_t bytes) {
    char* p = ws + off;
    off = (off + bytes + 255) & ~(size_t)255;
    return p;
  };
  unsigned short* W1t = (unsigned short*)alloc((size_t)NF * NH * 2);
  unsigned short* W2t = (unsigned short*)alloc((size_t)NH * NC * 2);
  unsigned short* h   = (unsigned short*)alloc((size_t)NN * NH * 2);
  unsigned short* h2  = (unsigned short*)alloc((size_t)NN * NH * 2);
  unsigned short* h3  = h;  // h dead after prop1; alias to save ws
  int* rowptr     = (int*)alloc((size_t)(NN + 1) * 4);
  int* partTotals = (int*)alloc((NPART + 1) * 4);
  int* partStart  = (int*)alloc((NPART + 1) * 4);
  int* partCursor = (int*)alloc((NPART + 1) * 4);
  int2* sedge     = (int2*)alloc((size_t)NE * 8);
  int2* tmp       = (int2*)alloc((size_t)NE * 8);

  k_zero0<<<4, 256, 0, stream>>>(partTotals);
  k_hist_conv<<<NBH + CONVB, 256, 0, stream>>>(ei, partTotals, W1, W2, W1t, W2t);
  k_pscan<<<1, 1024, 0, stream>>>(partTotals, partStart, partCursor, rowptr);
  k_part_gemm1<<<NBP + 782, 256, 0, stream>>>(ei, ew, partCursor, tmp, x, W1t, h);
  k_sortp<<<NPART, 256, 0, stream>>>(partStart, tmp, sedge, rowptr);
  k_prop1<<<NN / 4, 256, 0, stream>>>(rowptr, sedge, h, b1, h2);
  k_gemm2<<<(NN + 255) / 256, 256, 0, stream>>>(h2, W2t, h3);
  k_prop2<<<NN / 4, 256, 0, stream>>>(rowptr, sedge, h3, b2, out);
}